// Round 1
// baseline (176.891 us; speedup 1.0000x reference)
//
#include <hip/hip_runtime.h>
#include <math.h>

// ---------------------------------------------------------------------------
// Attention_2010044694851: x[4,2048,1024] fp32, w_qkv[1536,1024], w_out[1024,512],
// b_out[1024]  ->  out[4,2048,1024] fp32.
// Strategy: convert to bf16, run 4 MFMA GEMMs (all B^T layout, K-contiguous),
// causal-tiled sim + register softmax + causal-k-limited PV.
// ---------------------------------------------------------------------------

typedef __attribute__((ext_vector_type(8))) short bf16x8_t;
typedef __attribute__((ext_vector_type(4))) float f32x4_t;

__device__ __forceinline__ unsigned short f2bf(float f) {
  unsigned int u = __float_as_uint(f);
  u = (u + 0x7FFFu + ((u >> 16) & 1u)) >> 16;
  return (unsigned short)u;
}
__device__ __forceinline__ float bf2f(unsigned short h) {
  return __uint_as_float(((unsigned int)h) << 16);
}

// ---------------------------------------------------------------------------
// fp32 -> bf16 conversion (vectorized, grid-stride)
// ---------------------------------------------------------------------------
__global__ __launch_bounds__(256) void cvt_f32_bf16(const float* __restrict__ in,
                                                    unsigned short* __restrict__ out,
                                                    int n) {
  int stride = gridDim.x * blockDim.x * 4;
  for (int i = (blockIdx.x * blockDim.x + threadIdx.x) * 4; i < n; i += stride) {
    float4 f = *(const float4*)(in + i);
    ushort4 u;
    u.x = f2bf(f.x); u.y = f2bf(f.y); u.z = f2bf(f.z); u.w = f2bf(f.w);
    *(ushort4*)(out + i) = u;
  }
}

// ---------------------------------------------------------------------------
// V transpose: src [4][2048][512] -> dst [4][512][2048] (bf16)
// ---------------------------------------------------------------------------
__global__ __launch_bounds__(256) void transpose_v(const unsigned short* __restrict__ src,
                                                   unsigned short* __restrict__ dst) {
  __shared__ unsigned short t[64][66];
  const int n0 = blockIdx.x * 64, e0 = blockIdx.y * 64;
  const unsigned short* s = src + (size_t)blockIdx.z * 2048 * 512;
  unsigned short* d = dst + (size_t)blockIdx.z * 512 * 2048;
  const int tc = threadIdx.x & 15;
  const int tr = threadIdx.x >> 4;
#pragma unroll
  for (int rr = 0; rr < 64; rr += 16) {
    ushort4 u = *(const ushort4*)(s + (size_t)(n0 + tr + rr) * 512 + e0 + tc * 4);
    t[tr + rr][tc * 4 + 0] = u.x;
    t[tr + rr][tc * 4 + 1] = u.y;
    t[tr + rr][tc * 4 + 2] = u.z;
    t[tr + rr][tc * 4 + 3] = u.w;
  }
  __syncthreads();
#pragma unroll
  for (int rr = 0; rr < 64; rr += 16) {
    ushort4 u;
    u.x = t[tc * 4 + 0][tr + rr];
    u.y = t[tc * 4 + 1][tr + rr];
    u.z = t[tc * 4 + 2][tr + rr];
    u.w = t[tc * 4 + 3][tr + rr];
    *(ushort4*)(d + (size_t)(e0 + tr + rr) * 2048 + n0 + tc * 4) = u;
  }
}

// ---------------------------------------------------------------------------
// Causal row softmax in-place on sim [4][2048][2048] bf16.
// One wave per row. Zero-fills up to the 128-row-tile bound so the PV GEMM can
// run full 128x128 tiles with a per-row-tile K limit.
// ---------------------------------------------------------------------------
__global__ __launch_bounds__(256) void softmax_causal(unsigned short* __restrict__ sim) {
  const int lane = threadIdx.x & 63;
  const int rowg = blockIdx.x * 4 + (threadIdx.x >> 6);  // 0..8191
  const int i = rowg & 2047;                             // row within batch
  unsigned short* row = sim + (size_t)rowg * 2048;
  const int nv = i + 1;                    // valid length
  const int tb = ((i >> 7) + 1) << 7;      // 128-tile bound (zero-fill to here)
  const int nc = (nv + 255) >> 8;          // 256-element chunks holding valid data
  const int ns = (tb + 255) >> 8;          // chunks to store

  float v[32];
  float m = -1e30f;
#pragma unroll
  for (int c = 0; c < 8; ++c) {
    if (c < nc) {
      const int j0 = c * 256 + lane * 4;
      ushort4 u = *(const ushort4*)(row + j0);
      float f0 = bf2f(u.x), f1 = bf2f(u.y), f2 = bf2f(u.z), f3 = bf2f(u.w);
      v[c * 4 + 0] = (j0 + 0 < nv) ? f0 : -1e30f;
      v[c * 4 + 1] = (j0 + 1 < nv) ? f1 : -1e30f;
      v[c * 4 + 2] = (j0 + 2 < nv) ? f2 : -1e30f;
      v[c * 4 + 3] = (j0 + 3 < nv) ? f3 : -1e30f;
      m = fmaxf(m, fmaxf(fmaxf(v[c * 4], v[c * 4 + 1]), fmaxf(v[c * 4 + 2], v[c * 4 + 3])));
    }
  }
#pragma unroll
  for (int s = 32; s >= 1; s >>= 1) m = fmaxf(m, __shfl_xor(m, s));
  float sum = 0.f;
#pragma unroll
  for (int c = 0; c < 8; ++c) {
    if (c < nc) {
#pragma unroll
      for (int e = 0; e < 4; ++e) {
        float p = __expf(v[c * 4 + e] - m);
        v[c * 4 + e] = p;
        sum += p;
      }
    }
  }
#pragma unroll
  for (int s = 32; s >= 1; s >>= 1) sum += __shfl_xor(sum, s);
  const float inv = 1.0f / sum;
#pragma unroll
  for (int c = 0; c < 8; ++c) {
    if (c < ns) {
      const int j0 = c * 256 + lane * 4;
      ushort4 u;
      if (c < nc) {
        u.x = f2bf(v[c * 4 + 0] * inv);
        u.y = f2bf(v[c * 4 + 1] * inv);
        u.z = f2bf(v[c * 4 + 2] * inv);
        u.w = f2bf(v[c * 4 + 3] * inv);
      } else {
        u.x = u.y = u.z = u.w = 0;
      }
      *(ushort4*)(row + j0) = u;
    }
  }
}

// ---------------------------------------------------------------------------
// Generic bf16 B^T GEMM: C[M,N] = A[M,K] * B[N,K]^T, 128x128 tile, BK=32,
// 4 waves, global_load_lds(16B) staging, mfma 16x16x32. EPI selects epilogue:
//   0: QKV scatter (q*scale | k | v)   1: sim bf16   2: attn-out bf16
//   3: fp32 out + bias
// ---------------------------------------------------------------------------
template <int EPI>
__global__ __launch_bounds__(256) void gemm_bt(
    const unsigned short* __restrict__ A, const unsigned short* __restrict__ B,
    int M, int N, int K, long strideA, long strideB, int klim, int causal,
    void* __restrict__ O0, void* __restrict__ O1, void* __restrict__ O2,
    const float* __restrict__ bias, float qscale) {
  const int bm = blockIdx.x, bn = blockIdx.y, bz = blockIdx.z;
  if (causal && bn > bm) return;
  const int tid = threadIdx.x, lane = tid & 63, wave = tid >> 6;
  const int wr = wave >> 1, wc = wave & 1;

  __shared__ alignas(16) unsigned short As[128 * 32];
  __shared__ alignas(16) unsigned short Bs[128 * 32];

  const unsigned short* Ab = A + (size_t)bz * strideA + (size_t)bm * 128 * K;
  const unsigned short* Bb = B + (size_t)bz * strideB + (size_t)bn * 128 * K;

  const int kmax = klim ? min(K, (bm + 1) * 128) : K;
  const int nkt = kmax >> 5;

  f32x4_t acc[4][4] = {};
  const int loff = wave * 1024 + lane * 16;  // byte offset within a 4KB chunk

  for (int kt = 0; kt < nkt; ++kt) {
#pragma unroll
    for (int i = 0; i < 2; ++i) {
      const int o = i * 4096 + loff;  // byte offset in the 8KB tile
      const int r = o >> 6;           // tile row (64B per row)
      const int c = o & 63;
      const char* ga = (const char*)(Ab + (size_t)r * K) + (size_t)kt * 64 + c;
      const char* gb = (const char*)(Bb + (size_t)r * K) + (size_t)kt * 64 + c;
      __builtin_amdgcn_global_load_lds(
          (const __attribute__((address_space(1))) void*)ga,
          (__attribute__((address_space(3))) void*)((char*)As + o), 16, 0, 0);
      __builtin_amdgcn_global_load_lds(
          (const __attribute__((address_space(1))) void*)gb,
          (__attribute__((address_space(3))) void*)((char*)Bs + o), 16, 0, 0);
    }
    __syncthreads();
    bf16x8_t av[4], bv[4];
#pragma unroll
    for (int f = 0; f < 4; ++f) {
      av[f] = *(const bf16x8_t*)((const char*)As +
                                 (wr * 64 + f * 16 + (lane & 15)) * 64 + (lane >> 4) * 16);
      bv[f] = *(const bf16x8_t*)((const char*)Bs +
                                 (wc * 64 + f * 16 + (lane & 15)) * 64 + (lane >> 4) * 16);
    }
#pragma unroll
    for (int fi = 0; fi < 4; ++fi)
#pragma unroll
      for (int fj = 0; fj < 4; ++fj)
        acc[fi][fj] = __builtin_amdgcn_mfma_f32_16x16x32_bf16(av[fi], bv[fj], acc[fi][fj], 0, 0, 0);
    __syncthreads();
  }

#pragma unroll
  for (int fi = 0; fi < 4; ++fi) {
    const int row_l = wr * 64 + fi * 16 + (lane >> 4) * 4;
#pragma unroll
    for (int fj = 0; fj < 4; ++fj) {
      const int col = bn * 128 + wc * 64 + fj * 16 + (lane & 15);
#pragma unroll
      for (int r = 0; r < 4; ++r) {
        const int row = bm * 128 + row_l + r;
        float v = acc[fi][fj][r];
        if constexpr (EPI == 0) {
          // row in [0,8192) = b*2048+n ; col in [0,1536)
          if (col < 512)
            ((unsigned short*)O0)[(size_t)row * 512 + col] = f2bf(v * qscale);
          else if (col < 1024)
            ((unsigned short*)O1)[(size_t)row * 512 + (col - 512)] = f2bf(v);
          else
            ((unsigned short*)O2)[(size_t)row * 512 + (col - 1024)] = f2bf(v);
        } else if constexpr (EPI == 1) {
          ((unsigned short*)O0)[(size_t)bz * 2048 * 2048 + (size_t)row * 2048 + col] = f2bf(v);
        } else if constexpr (EPI == 2) {
          ((unsigned short*)O0)[(size_t)bz * 2048 * 512 + (size_t)row * 512 + col] = f2bf(v);
        } else {
          ((float*)O0)[(size_t)row * 1024 + col] = v + bias[col];
        }
      }
    }
  }
}

// ---------------------------------------------------------------------------
extern "C" void kernel_launch(void* const* d_in, const int* in_sizes, int n_in,
                              void* d_out, int out_size, void* d_ws, size_t ws_size,
                              hipStream_t stream) {
  const float* x = (const float*)d_in[0];      // [4,2048,1024]
  const float* w_qkv = (const float*)d_in[1];  // [1536,1024]
  const float* w_out = (const float*)d_in[2];  // [1024,512]
  const float* b_out = (const float*)d_in[3];  // [1024]
  float* out = (float*)d_out;                  // [4,2048,1024]

  char* ws = (char*)d_ws;
  size_t off = 0;
  auto alloc = [&](size_t bytes) {
    size_t o = off;
    off += (bytes + 255) & ~(size_t)255;
    return o;
  };
  unsigned short* xb = (unsigned short*)(ws + alloc((size_t)8192 * 1024 * 2));
  unsigned short* wqkvb = (unsigned short*)(ws + alloc((size_t)1536 * 1024 * 2));
  unsigned short* woutb = (unsigned short*)(ws + alloc((size_t)1024 * 512 * 2));
  unsigned short* qb = (unsigned short*)(ws + alloc((size_t)8192 * 512 * 2));
  unsigned short* kb = (unsigned short*)(ws + alloc((size_t)8192 * 512 * 2));
  unsigned short* vb = (unsigned short*)(ws + alloc((size_t)8192 * 512 * 2));
  unsigned short* vtb = (unsigned short*)(ws + alloc((size_t)8192 * 512 * 2));
  unsigned short* sim = (unsigned short*)(ws + alloc((size_t)4 * 2048 * 2048 * 2));
  unsigned short* ao = (unsigned short*)(ws + alloc((size_t)8192 * 512 * 2));

  const float scale = 1.0f / sqrtf(512.0f);

  // fp32 -> bf16
  cvt_f32_bf16<<<1024, 256, 0, stream>>>(x, xb, 8192 * 1024);
  cvt_f32_bf16<<<256, 256, 0, stream>>>(w_qkv, wqkvb, 1536 * 1024);
  cvt_f32_bf16<<<128, 256, 0, stream>>>(w_out, woutb, 1024 * 512);

  // QKV projection: [8192,1536] = xb[8192,1024] * wqkvb[1536,1024]^T
  gemm_bt<0><<<dim3(64, 12, 1), 256, 0, stream>>>(xb, wqkvb, 8192, 1536, 1024,
                                                  0, 0, 0, 0, qb, kb, vb, nullptr, scale);

  // V transpose for the PV GEMM's B^T layout
  transpose_v<<<dim3(32, 8, 4), 256, 0, stream>>>(vb, vtb);

  // sim = q*scale @ k^T, causal tile skip (only bn <= bm computed)
  gemm_bt<1><<<dim3(16, 16, 4), 256, 0, stream>>>(qb, kb, 2048, 2048, 512,
                                                  (long)2048 * 512, (long)2048 * 512,
                                                  0, 1, sim, nullptr, nullptr, nullptr, 0.f);

  // causal softmax rows (in-place, zero-fill to 128-tile bound)
  softmax_causal<<<2048, 256, 0, stream>>>(sim);

  // attn @ v : K limited to the causal bound per row-tile
  gemm_bt<2><<<dim3(16, 4, 4), 256, 0, stream>>>(sim, vtb, 2048, 512, 2048,
                                                 (long)2048 * 2048, (long)512 * 2048,
                                                 1, 0, ao, nullptr, nullptr, nullptr, 0.f);

  // output projection + bias -> fp32
  gemm_bt<3><<<dim3(64, 8, 1), 256, 0, stream>>>(ao, woutb, 8192, 1024, 512,
                                                 0, 0, 0, 0, out, nullptr, nullptr, b_out, 0.f);
}

// Round 2
// 162.785 us; speedup vs baseline: 1.0867x; 1.0867x over previous
//
#include <hip/hip_runtime.h>
#include <math.h>

// ---------------------------------------------------------------------------
// Attention_2010044694851: x[4,2048,1024] fp32, w_qkv[1536,1024], w_out[1024,512],
// b_out[1024]  ->  out[4,2048,1024] fp32.
// bf16 MFMA pipeline: cvt -> QKV GEMM -> V^T -> causal sim GEMM -> softmax ->
// PV GEMM (2-phase pipelined, 128x64 tile) -> proj GEMM.
// ---------------------------------------------------------------------------

typedef __attribute__((ext_vector_type(8))) short bf16x8_t;
typedef __attribute__((ext_vector_type(4))) float f32x4_t;

__device__ __forceinline__ unsigned short f2bf(float f) {
  unsigned int u = __float_as_uint(f);
  u = (u + 0x7FFFu + ((u >> 16) & 1u)) >> 16;
  return (unsigned short)u;
}
__device__ __forceinline__ float bf2f(unsigned short h) {
  return __uint_as_float(((unsigned int)h) << 16);
}

// ---------------------------------------------------------------------------
__global__ __launch_bounds__(256) void cvt_f32_bf16(const float* __restrict__ in,
                                                    unsigned short* __restrict__ out,
                                                    int n) {
  int stride = gridDim.x * blockDim.x * 4;
  for (int i = (blockIdx.x * blockDim.x + threadIdx.x) * 4; i < n; i += stride) {
    float4 f = *(const float4*)(in + i);
    ushort4 u;
    u.x = f2bf(f.x); u.y = f2bf(f.y); u.z = f2bf(f.z); u.w = f2bf(f.w);
    *(ushort4*)(out + i) = u;
  }
}

// ---------------------------------------------------------------------------
// V transpose: src [4][2048][512] -> dst [4][512][2048] (bf16)
// ---------------------------------------------------------------------------
__global__ __launch_bounds__(256) void transpose_v(const unsigned short* __restrict__ src,
                                                   unsigned short* __restrict__ dst) {
  __shared__ unsigned short t[64][66];
  const int n0 = blockIdx.x * 64, e0 = blockIdx.y * 64;
  const unsigned short* s = src + (size_t)blockIdx.z * 2048 * 512;
  unsigned short* d = dst + (size_t)blockIdx.z * 512 * 2048;
  const int tc = threadIdx.x & 15;
  const int tr = threadIdx.x >> 4;
#pragma unroll
  for (int rr = 0; rr < 64; rr += 16) {
    ushort4 u = *(const ushort4*)(s + (size_t)(n0 + tr + rr) * 512 + e0 + tc * 4);
    t[tr + rr][tc * 4 + 0] = u.x;
    t[tr + rr][tc * 4 + 1] = u.y;
    t[tr + rr][tc * 4 + 2] = u.z;
    t[tr + rr][tc * 4 + 3] = u.w;
  }
  __syncthreads();
#pragma unroll
  for (int rr = 0; rr < 64; rr += 16) {
    ushort4 u;
    u.x = t[tc * 4 + 0][tr + rr];
    u.y = t[tc * 4 + 1][tr + rr];
    u.z = t[tc * 4 + 2][tr + rr];
    u.w = t[tc * 4 + 3][tr + rr];
    *(ushort4*)(d + (size_t)(e0 + tr + rr) * 2048 + n0 + tc * 4) = u;
  }
}

// ---------------------------------------------------------------------------
// Causal row softmax in-place on sim [4][2048][2048] bf16. One wave per row;
// zero-fills to the 128-tile bound so PV can run full tiles with a K limit.
// ---------------------------------------------------------------------------
__global__ __launch_bounds__(256) void softmax_causal(unsigned short* __restrict__ sim) {
  const int lane = threadIdx.x & 63;
  const int rowg = blockIdx.x * 4 + (threadIdx.x >> 6);  // 0..8191
  const int i = rowg & 2047;
  unsigned short* row = sim + (size_t)rowg * 2048;
  const int nv = i + 1;
  const int tb = ((i >> 7) + 1) << 7;
  const int nc = (nv + 255) >> 8;
  const int ns = (tb + 255) >> 8;

  float v[32];
  float m = -1e30f;
#pragma unroll
  for (int c = 0; c < 8; ++c) {
    if (c < nc) {
      const int j0 = c * 256 + lane * 4;
      ushort4 u = *(const ushort4*)(row + j0);
      float f0 = bf2f(u.x), f1 = bf2f(u.y), f2 = bf2f(u.z), f3 = bf2f(u.w);
      v[c * 4 + 0] = (j0 + 0 < nv) ? f0 : -1e30f;
      v[c * 4 + 1] = (j0 + 1 < nv) ? f1 : -1e30f;
      v[c * 4 + 2] = (j0 + 2 < nv) ? f2 : -1e30f;
      v[c * 4 + 3] = (j0 + 3 < nv) ? f3 : -1e30f;
      m = fmaxf(m, fmaxf(fmaxf(v[c * 4], v[c * 4 + 1]), fmaxf(v[c * 4 + 2], v[c * 4 + 3])));
    }
  }
#pragma unroll
  for (int s = 32; s >= 1; s >>= 1) m = fmaxf(m, __shfl_xor(m, s));
  float sum = 0.f;
#pragma unroll
  for (int c = 0; c < 8; ++c) {
    if (c < nc) {
#pragma unroll
      for (int e = 0; e < 4; ++e) {
        float p = __expf(v[c * 4 + e] - m);
        v[c * 4 + e] = p;
        sum += p;
      }
    }
  }
#pragma unroll
  for (int s = 32; s >= 1; s >>= 1) sum += __shfl_xor(sum, s);
  const float inv = 1.0f / sum;
#pragma unroll
  for (int c = 0; c < 8; ++c) {
    if (c < ns) {
      const int j0 = c * 256 + lane * 4;
      ushort4 u;
      if (c < nc) {
        u.x = f2bf(v[c * 4 + 0] * inv);
        u.y = f2bf(v[c * 4 + 1] * inv);
        u.z = f2bf(v[c * 4 + 2] * inv);
        u.w = f2bf(v[c * 4 + 3] * inv);
      } else {
        u.x = u.y = u.z = u.w = 0;
      }
      *(ushort4*)(row + j0) = u;
    }
  }
}

// ---------------------------------------------------------------------------
// bf16 B^T GEMM: C[M,N] = A[M,K] * B[N,K]^T. Tile BMxBN, BK=32, 4 waves (2x2).
// PIPE=1: explicit 2-phase double-buffered pipeline (raw s_barrier + counted
// waitcnt) for low-occupancy / latency-bound dispatches.
// EPI: 0 QKV scatter (q*scale|k|v)  1 sim bf16  2 attn-out bf16  3 fp32+bias
// ---------------------------------------------------------------------------
template <int EPI, int BM, int BN, int PIPE>
__global__ __launch_bounds__(256) void gemm_bt(
    const unsigned short* __restrict__ A, const unsigned short* __restrict__ B,
    int M, int N, int K, long strideA, long strideB, int klim, int causal,
    void* __restrict__ O0, void* __restrict__ O1, void* __restrict__ O2,
    const float* __restrict__ bias, float qscale) {
  const int bm = blockIdx.x, bn = blockIdx.y, bz = blockIdx.z;
  if (causal && bn > bm) return;
  const int tid = threadIdx.x, lane = tid & 63, wave = tid >> 6;
  const int wr = wave >> 1, wc = wave & 1;
  constexpr int FM = BM / 32, FN = BN / 32;   // 16x16 frags per wave
  constexpr int AR = BM / 64, BR = BN / 64;   // 4KB staging rounds

  __shared__ alignas(16) unsigned short As[PIPE ? 2 : 1][BM * 32];
  __shared__ alignas(16) unsigned short Bs[PIPE ? 2 : 1][BN * 32];

  const unsigned short* Ab = A + (size_t)bz * strideA + (size_t)bm * BM * K;
  const unsigned short* Bb = B + (size_t)bz * strideB + (size_t)bn * BN * K;

  const int kmax = klim ? min(K, (bm + 1) * BM) : K;
  const int nkt = kmax >> 5;

  auto stage = [&](int buf, int kt) {
    const int loff = tid * 16;
#pragma unroll
    for (int i = 0; i < AR; ++i) {
      const int o = i * 4096 + loff;
      const int r = o >> 6, c = o & 63;
      __builtin_amdgcn_global_load_lds(
          (const __attribute__((address_space(1))) void*)((const char*)(Ab + (size_t)r * K) + (size_t)kt * 64 + c),
          (__attribute__((address_space(3))) void*)((char*)As[buf] + o), 16, 0, 0);
    }
#pragma unroll
    for (int i = 0; i < BR; ++i) {
      const int o = i * 4096 + loff;
      const int r = o >> 6, c = o & 63;
      __builtin_amdgcn_global_load_lds(
          (const __attribute__((address_space(1))) void*)((const char*)(Bb + (size_t)r * K) + (size_t)kt * 64 + c),
          (__attribute__((address_space(3))) void*)((char*)Bs[buf] + o), 16, 0, 0);
    }
  };

  f32x4_t acc[FM][FN] = {};

  if constexpr (PIPE) {
    stage(0, 0);
    asm volatile("s_waitcnt vmcnt(0)" ::: "memory");
    __builtin_amdgcn_s_barrier();
    int cur = 0;
    for (int kt = 0; kt < nkt; ++kt) {
      if (kt + 1 < nkt) stage(cur ^ 1, kt + 1);   // issue next-tile loads
      __builtin_amdgcn_sched_barrier(0);
      bf16x8_t av[FM], bv[FN];
#pragma unroll
      for (int f = 0; f < FM; ++f)
        av[f] = *(const bf16x8_t*)((const char*)As[cur] +
                                   (wr * (BM / 2) + f * 16 + (lane & 15)) * 64 + (lane >> 4) * 16);
#pragma unroll
      for (int f = 0; f < FN; ++f)
        bv[f] = *(const bf16x8_t*)((const char*)Bs[cur] +
                                   (wc * (BN / 2) + f * 16 + (lane & 15)) * 64 + (lane >> 4) * 16);
      asm volatile("s_waitcnt lgkmcnt(0)" ::: "memory");
      __builtin_amdgcn_sched_barrier(0);
      __builtin_amdgcn_s_setprio(1);
#pragma unroll
      for (int fi = 0; fi < FM; ++fi)
#pragma unroll
        for (int fj = 0; fj < FN; ++fj)
          acc[fi][fj] = __builtin_amdgcn_mfma_f32_16x16x32_bf16(av[fi], bv[fj], acc[fi][fj], 0, 0, 0);
      __builtin_amdgcn_s_setprio(0);
      __builtin_amdgcn_sched_barrier(0);
      if (kt + 1 < nkt) asm volatile("s_waitcnt vmcnt(0)" ::: "memory");
      __builtin_amdgcn_s_barrier();
      cur ^= 1;
    }
  } else {
    for (int kt = 0; kt < nkt; ++kt) {
      stage(0, kt);
      __syncthreads();
      bf16x8_t av[FM], bv[FN];
#pragma unroll
      for (int f = 0; f < FM; ++f)
        av[f] = *(const bf16x8_t*)((const char*)As[0] +
                                   (wr * (BM / 2) + f * 16 + (lane & 15)) * 64 + (lane >> 4) * 16);
#pragma unroll
      for (int f = 0; f < FN; ++f)
        bv[f] = *(const bf16x8_t*)((const char*)Bs[0] +
                                   (wc * (BN / 2) + f * 16 + (lane & 15)) * 64 + (lane >> 4) * 16);
#pragma unroll
      for (int fi = 0; fi < FM; ++fi)
#pragma unroll
        for (int fj = 0; fj < FN; ++fj)
          acc[fi][fj] = __builtin_amdgcn_mfma_f32_16x16x32_bf16(av[fi], bv[fj], acc[fi][fj], 0, 0, 0);
      __syncthreads();
    }
  }

#pragma unroll
  for (int fi = 0; fi < FM; ++fi) {
    const int row_l = wr * (BM / 2) + fi * 16 + ((lane >> 4) << 2);
#pragma unroll
    for (int fj = 0; fj < FN; ++fj) {
      const int col = bn * BN + wc * (BN / 2) + fj * 16 + (lane & 15);
#pragma unroll
      for (int r = 0; r < 4; ++r) {
        const int row = bm * BM + row_l + r;
        float v = acc[fi][fj][r];
        if constexpr (EPI == 0) {
          if (col < 512)
            ((unsigned short*)O0)[(size_t)row * 512 + col] = f2bf(v * qscale);
          else if (col < 1024)
            ((unsigned short*)O1)[(size_t)row * 512 + (col - 512)] = f2bf(v);
          else
            ((unsigned short*)O2)[(size_t)row * 512 + (col - 1024)] = f2bf(v);
        } else if constexpr (EPI == 1) {
          ((unsigned short*)O0)[(size_t)bz * 2048 * 2048 + (size_t)row * 2048 + col] = f2bf(v);
        } else if constexpr (EPI == 2) {
          ((unsigned short*)O0)[(size_t)bz * 2048 * 512 + (size_t)row * 512 + col] = f2bf(v);
        } else {
          ((float*)O0)[(size_t)row * 1024 + col] = v + bias[col];
        }
      }
    }
  }
}

// ---------------------------------------------------------------------------
extern "C" void kernel_launch(void* const* d_in, const int* in_sizes, int n_in,
                              void* d_out, int out_size, void* d_ws, size_t ws_size,
                              hipStream_t stream) {
  const float* x = (const float*)d_in[0];
  const float* w_qkv = (const float*)d_in[1];
  const float* w_out = (const float*)d_in[2];
  const float* b_out = (const float*)d_in[3];
  float* out = (float*)d_out;

  char* ws = (char*)d_ws;
  size_t off = 0;
  auto alloc = [&](size_t bytes) {
    size_t o = off;
    off += (bytes + 255) & ~(size_t)255;
    return o;
  };
  unsigned short* xb = (unsigned short*)(ws + alloc((size_t)8192 * 1024 * 2));
  unsigned short* wqkvb = (unsigned short*)(ws + alloc((size_t)1536 * 1024 * 2));
  unsigned short* woutb = (unsigned short*)(ws + alloc((size_t)1024 * 512 * 2));
  unsigned short* qb = (unsigned short*)(ws + alloc((size_t)8192 * 512 * 2));
  unsigned short* kb = (unsigned short*)(ws + alloc((size_t)8192 * 512 * 2));
  unsigned short* vb = (unsigned short*)(ws + alloc((size_t)8192 * 512 * 2));
  unsigned short* vtb = (unsigned short*)(ws + alloc((size_t)8192 * 512 * 2));
  unsigned short* sim = (unsigned short*)(ws + alloc((size_t)4 * 2048 * 2048 * 2));
  unsigned short* ao = (unsigned short*)(ws + alloc((size_t)8192 * 512 * 2));

  const float scale = 1.0f / sqrtf(512.0f);

  cvt_f32_bf16<<<1024, 256, 0, stream>>>(x, xb, 8192 * 1024);
  cvt_f32_bf16<<<256, 256, 0, stream>>>(w_qkv, wqkvb, 1536 * 1024);
  cvt_f32_bf16<<<128, 256, 0, stream>>>(w_out, woutb, 1024 * 512);

  // QKV: [8192,1536] = xb[8192,1024] * wqkvb^T — 768 blocks (3/CU), plain path
  gemm_bt<0, 128, 128, 0><<<dim3(64, 12, 1), 256, 0, stream>>>(
      xb, wqkvb, 8192, 1536, 1024, 0, 0, 0, 0, qb, kb, vb, nullptr, scale);

  transpose_v<<<dim3(32, 8, 4), 256, 0, stream>>>(vb, vtb);

  // sim = q*scale @ k^T, causal tile skip — pipelined
  gemm_bt<1, 128, 128, 1><<<dim3(16, 16, 4), 256, 0, stream>>>(
      qb, kb, 2048, 2048, 512, (long)2048 * 512, (long)2048 * 512,
      0, 1, sim, nullptr, nullptr, nullptr, 0.f);

  softmax_causal<<<2048, 256, 0, stream>>>(sim);

  // attn @ v : 128x64 tile -> 512 blocks, K causal-limited — pipelined
  gemm_bt<2, 128, 64, 1><<<dim3(16, 8, 4), 256, 0, stream>>>(
      sim, vtb, 2048, 512, 2048, (long)2048 * 2048, (long)512 * 2048,
      1, 0, ao, nullptr, nullptr, nullptr, 0.f);

  // out = ao @ w_out^T + b — pipelined
  gemm_bt<3, 128, 128, 1><<<dim3(64, 8, 1), 256, 0, stream>>>(
      ao, woutb, 8192, 1024, 512, 0, 0, 0, 0, out, nullptr, nullptr, b_out, 0.f);
}

// Round 3
// 142.252 us; speedup vs baseline: 1.2435x; 1.1443x over previous
//
#include <hip/hip_runtime.h>
#include <math.h>

// ---------------------------------------------------------------------------
// Attention_2010044694851: x[4,2048,1024] fp32, w_qkv[1536,1024], w_out[1024,512],
// b_out[1024] -> out[4,2048,1024] fp32.
// bf16 MFMA pipeline: cvt -> QKV GEMM -> V^T -> causal sim GEMM -> softmax ->
// PV GEMM -> proj GEMM. GEMMs: 3-buffer counted-vmcnt pipeline (T3/T4-style),
// bank-conflict-free swizzled LDS (T2, rule-21 both-sides), setprio MFMA (T5).
// ---------------------------------------------------------------------------

typedef __attribute__((ext_vector_type(8))) short bf16x8_t;
typedef __attribute__((ext_vector_type(4))) float f32x4_t;

__device__ __forceinline__ unsigned short f2bf(float f) {
  unsigned int u = __float_as_uint(f);
  u = (u + 0x7FFFu + ((u >> 16) & 1u)) >> 16;
  return (unsigned short)u;
}
__device__ __forceinline__ float bf2f(unsigned short h) {
  return __uint_as_float(((unsigned int)h) << 16);
}

template <int N>
__device__ __forceinline__ void wait_vmcnt() {
  if constexpr (N == 0) asm volatile("s_waitcnt vmcnt(0)" ::: "memory");
  else if constexpr (N == 3) asm volatile("s_waitcnt vmcnt(3)" ::: "memory");
  else if constexpr (N == 4) asm volatile("s_waitcnt vmcnt(4)" ::: "memory");
  else if constexpr (N == 6) asm volatile("s_waitcnt vmcnt(6)" ::: "memory");
}

// ---------------------------------------------------------------------------
__global__ __launch_bounds__(256) void cvt_f32_bf16(const float* __restrict__ in,
                                                    unsigned short* __restrict__ out,
                                                    int n) {
  int stride = gridDim.x * blockDim.x * 4;
  for (int i = (blockIdx.x * blockDim.x + threadIdx.x) * 4; i < n; i += stride) {
    float4 f = *(const float4*)(in + i);
    ushort4 u;
    u.x = f2bf(f.x); u.y = f2bf(f.y); u.z = f2bf(f.z); u.w = f2bf(f.w);
    *(ushort4*)(out + i) = u;
  }
}

// ---------------------------------------------------------------------------
// V transpose: src [4][2048][512] -> dst [4][512][2048] (bf16)
// ---------------------------------------------------------------------------
__global__ __launch_bounds__(256) void transpose_v(const unsigned short* __restrict__ src,
                                                   unsigned short* __restrict__ dst) {
  __shared__ unsigned short t[64][66];
  const int n0 = blockIdx.x * 64, e0 = blockIdx.y * 64;
  const unsigned short* s = src + (size_t)blockIdx.z * 2048 * 512;
  unsigned short* d = dst + (size_t)blockIdx.z * 512 * 2048;
  const int tc = threadIdx.x & 15;
  const int tr = threadIdx.x >> 4;
#pragma unroll
  for (int rr = 0; rr < 64; rr += 16) {
    ushort4 u = *(const ushort4*)(s + (size_t)(n0 + tr + rr) * 512 + e0 + tc * 4);
    t[tr + rr][tc * 4 + 0] = u.x;
    t[tr + rr][tc * 4 + 1] = u.y;
    t[tr + rr][tc * 4 + 2] = u.z;
    t[tr + rr][tc * 4 + 3] = u.w;
  }
  __syncthreads();
#pragma unroll
  for (int rr = 0; rr < 64; rr += 16) {
    ushort4 u;
    u.x = t[tc * 4 + 0][tr + rr];
    u.y = t[tc * 4 + 1][tr + rr];
    u.z = t[tc * 4 + 2][tr + rr];
    u.w = t[tc * 4 + 3][tr + rr];
    *(ushort4*)(d + (size_t)(e0 + tr + rr) * 2048 + n0 + tc * 4) = u;
  }
}

// ---------------------------------------------------------------------------
// Causal row softmax in-place on sim [4][2048][2048] bf16. One wave per row;
// zero-fills to the 128-tile bound so PV can run full tiles with a K limit.
// ---------------------------------------------------------------------------
__global__ __launch_bounds__(256) void softmax_causal(unsigned short* __restrict__ sim) {
  const int lane = threadIdx.x & 63;
  const int rowg = blockIdx.x * 4 + (threadIdx.x >> 6);
  const int i = rowg & 2047;
  unsigned short* row = sim + (size_t)rowg * 2048;
  const int nv = i + 1;
  const int tb = ((i >> 7) + 1) << 7;
  const int nc = (nv + 255) >> 8;
  const int ns = (tb + 255) >> 8;

  float v[32];
  float m = -1e30f;
#pragma unroll
  for (int c = 0; c < 8; ++c) {
    if (c < nc) {
      const int j0 = c * 256 + lane * 4;
      ushort4 u = *(const ushort4*)(row + j0);
      float f0 = bf2f(u.x), f1 = bf2f(u.y), f2 = bf2f(u.z), f3 = bf2f(u.w);
      v[c * 4 + 0] = (j0 + 0 < nv) ? f0 : -1e30f;
      v[c * 4 + 1] = (j0 + 1 < nv) ? f1 : -1e30f;
      v[c * 4 + 2] = (j0 + 2 < nv) ? f2 : -1e30f;
      v[c * 4 + 3] = (j0 + 3 < nv) ? f3 : -1e30f;
      m = fmaxf(m, fmaxf(fmaxf(v[c * 4], v[c * 4 + 1]), fmaxf(v[c * 4 + 2], v[c * 4 + 3])));
    }
  }
#pragma unroll
  for (int s = 32; s >= 1; s >>= 1) m = fmaxf(m, __shfl_xor(m, s));
  float sum = 0.f;
#pragma unroll
  for (int c = 0; c < 8; ++c) {
    if (c < nc) {
#pragma unroll
      for (int e = 0; e < 4; ++e) {
        float p = __expf(v[c * 4 + e] - m);
        v[c * 4 + e] = p;
        sum += p;
      }
    }
  }
#pragma unroll
  for (int s = 32; s >= 1; s >>= 1) sum += __shfl_xor(sum, s);
  const float inv = 1.0f / sum;
#pragma unroll
  for (int c = 0; c < 8; ++c) {
    if (c < ns) {
      const int j0 = c * 256 + lane * 4;
      ushort4 u;
      if (c < nc) {
        u.x = f2bf(v[c * 4 + 0] * inv);
        u.y = f2bf(v[c * 4 + 1] * inv);
        u.z = f2bf(v[c * 4 + 2] * inv);
        u.w = f2bf(v[c * 4 + 3] * inv);
      } else {
        u.x = u.y = u.z = u.w = 0;
      }
      *(ushort4*)(row + j0) = u;
    }
  }
}

// ---------------------------------------------------------------------------
// bf16 B^T GEMM: C[M,N] = A[M,K] * B[N,K]^T. Tile BMxBN, BK=32, 4 waves (2x2).
// 3 LDS buffers, 2 tiles in flight, steady-state wait = vmcnt(loads/tile).
// LDS slot swizzle: phys16Bslot = hi ^ ((row>>1)&3), applied to BOTH the
// pre-swizzled global source (stage) and the ds_read address (rule 21).
// EPI: 0 QKV scatter (q*scale|k|v)  1 sim bf16  2 attn-out bf16  3 fp32+bias
// ---------------------------------------------------------------------------
template <int EPI, int BM, int BN>
__global__ __launch_bounds__(256) void gemm_bt(
    const unsigned short* __restrict__ A, const unsigned short* __restrict__ B,
    int M, int N, int K, long strideA, long strideB, int klim, int causal,
    void* __restrict__ O0, void* __restrict__ O1, void* __restrict__ O2,
    const float* __restrict__ bias, float qscale) {
  const int bm = blockIdx.x, bn = blockIdx.y, bz = blockIdx.z;
  if (causal && bn > bm) return;
  const int tid = threadIdx.x, lane = tid & 63, wave = tid >> 6;
  const int wr = wave >> 1, wc = wave & 1;
  constexpr int FM = BM / 32, FN = BN / 32;  // 16x16 frags per wave
  constexpr int AR = BM / 64, BR = BN / 64;  // 4KB staging rounds
  constexpr int L = AR + BR;                 // global_load_lds per tile per thread

  __shared__ alignas(16) unsigned short As[3][BM * 32];
  __shared__ alignas(16) unsigned short Bs[3][BN * 32];

  const unsigned short* Ab = A + (size_t)bz * strideA + (size_t)bm * BM * K;
  const unsigned short* Bb = B + (size_t)bz * strideB + (size_t)bn * BN * K;

  const int kmax = klim ? min(K, (bm + 1) * BM) : K;
  const int nkt = kmax >> 5;

  auto stage = [&](int buf, int kt) {
    const int loff = tid * 16;
#pragma unroll
    for (int i = 0; i < AR; ++i) {
      const int o = i * 4096 + loff;
      const int r = o >> 6;
      const int sl = ((o >> 4) & 3) ^ ((r >> 1) & 3);  // logical slot for phys o
      __builtin_amdgcn_global_load_lds(
          (const __attribute__((address_space(1))) void*)(
              (const char*)(Ab + (size_t)r * K) + (size_t)kt * 64 + sl * 16),
          (__attribute__((address_space(3))) void*)((char*)As[buf] + o), 16, 0, 0);
    }
#pragma unroll
    for (int i = 0; i < BR; ++i) {
      const int o = i * 4096 + loff;
      const int r = o >> 6;
      const int sl = ((o >> 4) & 3) ^ ((r >> 1) & 3);
      __builtin_amdgcn_global_load_lds(
          (const __attribute__((address_space(1))) void*)(
              (const char*)(Bb + (size_t)r * K) + (size_t)kt * 64 + sl * 16),
          (__attribute__((address_space(3))) void*)((char*)Bs[buf] + o), 16, 0, 0);
    }
  };

  f32x4_t acc[FM][FN] = {};

  stage(0, 0);
  if (nkt > 1) stage(1, 1);
  int cur = 0;
  for (int kt = 0; kt < nkt; ++kt) {
    if (kt + 1 < nkt) wait_vmcnt<L>();  // tile kt landed; kt+1 stays in flight
    else wait_vmcnt<0>();
    __builtin_amdgcn_s_barrier();

    bf16x8_t av[FM], bv[FN];
#pragma unroll
    for (int f = 0; f < FM; ++f) {
      const int row = wr * (BM / 2) + f * 16 + (lane & 15);
      const int sp = (lane >> 4) ^ ((row >> 1) & 3);
      av[f] = *(const bf16x8_t*)((const char*)As[cur] + row * 64 + sp * 16);
    }
#pragma unroll
    for (int f = 0; f < FN; ++f) {
      const int row = wc * (BN / 2) + f * 16 + (lane & 15);
      const int sp = (lane >> 4) ^ ((row >> 1) & 3);
      bv[f] = *(const bf16x8_t*)((const char*)Bs[cur] + row * 64 + sp * 16);
    }
    if (kt + 2 < nkt) {
      int nb = cur + 2;
      if (nb >= 3) nb -= 3;
      stage(nb, kt + 2);  // overwrites buf of tile kt-1: safe post-barrier
    }
    asm volatile("s_waitcnt lgkmcnt(0)" ::: "memory");
    __builtin_amdgcn_sched_barrier(0);
    __builtin_amdgcn_s_setprio(1);
#pragma unroll
    for (int fi = 0; fi < FM; ++fi)
#pragma unroll
      for (int fj = 0; fj < FN; ++fj)
        acc[fi][fj] = __builtin_amdgcn_mfma_f32_16x16x32_bf16(av[fi], bv[fj], acc[fi][fj], 0, 0, 0);
    __builtin_amdgcn_s_setprio(0);
    __builtin_amdgcn_sched_barrier(0);
    cur = (cur + 1 == 3) ? 0 : cur + 1;
  }

#pragma unroll
  for (int fi = 0; fi < FM; ++fi) {
    const int row_l = wr * (BM / 2) + fi * 16 + ((lane >> 4) << 2);
#pragma unroll
    for (int fj = 0; fj < FN; ++fj) {
      const int col = bn * BN + wc * (BN / 2) + fj * 16 + (lane & 15);
#pragma unroll
      for (int r = 0; r < 4; ++r) {
        const int row = bm * BM + row_l + r;
        float v = acc[fi][fj][r];
        if constexpr (EPI == 0) {
          if (col < 512)
            ((unsigned short*)O0)[(size_t)row * 512 + col] = f2bf(v * qscale);
          else if (col < 1024)
            ((unsigned short*)O1)[(size_t)row * 512 + (col - 512)] = f2bf(v);
          else
            ((unsigned short*)O2)[(size_t)row * 512 + (col - 1024)] = f2bf(v);
        } else if constexpr (EPI == 1) {
          ((unsigned short*)O0)[(size_t)bz * 2048 * 2048 + (size_t)row * 2048 + col] = f2bf(v);
        } else if constexpr (EPI == 2) {
          ((unsigned short*)O0)[(size_t)bz * 2048 * 512 + (size_t)row * 512 + col] = f2bf(v);
        } else {
          ((float*)O0)[(size_t)row * 1024 + col] = v + bias[col];
        }
      }
    }
  }
}

// ---------------------------------------------------------------------------
extern "C" void kernel_launch(void* const* d_in, const int* in_sizes, int n_in,
                              void* d_out, int out_size, void* d_ws, size_t ws_size,
                              hipStream_t stream) {
  const float* x = (const float*)d_in[0];
  const float* w_qkv = (const float*)d_in[1];
  const float* w_out = (const float*)d_in[2];
  const float* b_out = (const float*)d_in[3];
  float* out = (float*)d_out;

  char* ws = (char*)d_ws;
  size_t off = 0;
  auto alloc = [&](size_t bytes) {
    size_t o = off;
    off += (bytes + 255) & ~(size_t)255;
    return o;
  };
  unsigned short* xb = (unsigned short*)(ws + alloc((size_t)8192 * 1024 * 2));
  unsigned short* wqkvb = (unsigned short*)(ws + alloc((size_t)1536 * 1024 * 2));
  unsigned short* woutb = (unsigned short*)(ws + alloc((size_t)1024 * 512 * 2));
  unsigned short* qb = (unsigned short*)(ws + alloc((size_t)8192 * 512 * 2));
  unsigned short* kb = (unsigned short*)(ws + alloc((size_t)8192 * 512 * 2));
  unsigned short* vb = (unsigned short*)(ws + alloc((size_t)8192 * 512 * 2));
  unsigned short* vtb = (unsigned short*)(ws + alloc((size_t)8192 * 512 * 2));
  unsigned short* sim = (unsigned short*)(ws + alloc((size_t)4 * 2048 * 2048 * 2));
  unsigned short* ao = (unsigned short*)(ws + alloc((size_t)8192 * 512 * 2));

  const float scale = 1.0f / sqrtf(512.0f);

  cvt_f32_bf16<<<1024, 256, 0, stream>>>(x, xb, 8192 * 1024);
  cvt_f32_bf16<<<256, 256, 0, stream>>>(w_qkv, wqkvb, 1536 * 1024);
  cvt_f32_bf16<<<128, 256, 0, stream>>>(w_out, woutb, 1024 * 512);

  // QKV: [8192,1536] = xb[8192,1024] * wqkvb^T
  gemm_bt<0, 128, 128><<<dim3(64, 12, 1), 256, 0, stream>>>(
      xb, wqkvb, 8192, 1536, 1024, 0, 0, 0, 0, qb, kb, vb, nullptr, scale);

  transpose_v<<<dim3(32, 8, 4), 256, 0, stream>>>(vb, vtb);

  // sim = q*scale @ k^T, causal tile skip
  gemm_bt<1, 128, 128><<<dim3(16, 16, 4), 256, 0, stream>>>(
      qb, kb, 2048, 2048, 512, (long)2048 * 512, (long)2048 * 512,
      0, 1, sim, nullptr, nullptr, nullptr, 0.f);

  softmax_causal<<<2048, 256, 0, stream>>>(sim);

  // attn @ v : 128x64 tile, K causal-limited
  gemm_bt<2, 128, 64><<<dim3(16, 8, 4), 256, 0, stream>>>(
      sim, vtb, 2048, 512, 2048, (long)2048 * 2048, (long)512 * 2048,
      1, 0, ao, nullptr, nullptr, nullptr, 0.f);

  // out = ao @ w_out^T + b
  gemm_bt<3, 128, 128><<<dim3(64, 8, 1), 256, 0, stream>>>(
      ao, woutb, 8192, 1024, 512, 0, 0, 0, 0, out, nullptr, nullptr, b_out, 0.f);
}

// Round 4
// 136.563 us; speedup vs baseline: 1.2953x; 1.0417x over previous
//
#include <hip/hip_runtime.h>
#include <math.h>

// ---------------------------------------------------------------------------
// Attention_2010044694851: x[4,2048,1024] fp32, w_qkv[1536,1024], w_out[1024,512],
// b_out[1024] -> out[4,2048,1024] fp32.
// bf16 MFMA pipeline: cvt -> QKV GEMM (128x192 tile, ratio 2.4) -> V^T ->
// causal sim GEMM -> softmax -> PV GEMM -> proj GEMM.
// GEMM core: 3-buffer counted-vmcnt pipeline, swizzled LDS (conflict-free,
// rule-21 both-sides), setprio MFMA.
// ---------------------------------------------------------------------------

typedef __attribute__((ext_vector_type(8))) short bf16x8_t;
typedef __attribute__((ext_vector_type(4))) float f32x4_t;

__device__ __forceinline__ unsigned short f2bf(float f) {
  unsigned int u = __float_as_uint(f);
  u = (u + 0x7FFFu + ((u >> 16) & 1u)) >> 16;
  return (unsigned short)u;
}
__device__ __forceinline__ float bf2f(unsigned short h) {
  return __uint_as_float(((unsigned int)h) << 16);
}

template <int N>
__device__ __forceinline__ void wait_vmcnt() {
  if constexpr (N == 0) asm volatile("s_waitcnt vmcnt(0)" ::: "memory");
  else if constexpr (N == 3) asm volatile("s_waitcnt vmcnt(3)" ::: "memory");
  else if constexpr (N == 4) asm volatile("s_waitcnt vmcnt(4)" ::: "memory");
  else if constexpr (N == 5) asm volatile("s_waitcnt vmcnt(5)" ::: "memory");
  else if constexpr (N == 6) asm volatile("s_waitcnt vmcnt(6)" ::: "memory");
}

// ---------------------------------------------------------------------------
// fused fp32 -> bf16 conversion for all three inputs (one launch)
// ---------------------------------------------------------------------------
__global__ __launch_bounds__(256) void cvt_all(
    const float* __restrict__ x, unsigned short* __restrict__ xb, int nx,
    const float* __restrict__ w1, unsigned short* __restrict__ w1b, int n1,
    const float* __restrict__ w2, unsigned short* __restrict__ w2b, int n2) {
  const int stride = gridDim.x * blockDim.x * 4;
  const int t0 = (blockIdx.x * blockDim.x + threadIdx.x) * 4;
  for (int i = t0; i < nx; i += stride) {
    float4 f = *(const float4*)(x + i);
    ushort4 u;
    u.x = f2bf(f.x); u.y = f2bf(f.y); u.z = f2bf(f.z); u.w = f2bf(f.w);
    *(ushort4*)(xb + i) = u;
  }
  for (int i = t0; i < n1; i += stride) {
    float4 f = *(const float4*)(w1 + i);
    ushort4 u;
    u.x = f2bf(f.x); u.y = f2bf(f.y); u.z = f2bf(f.z); u.w = f2bf(f.w);
    *(ushort4*)(w1b + i) = u;
  }
  for (int i = t0; i < n2; i += stride) {
    float4 f = *(const float4*)(w2 + i);
    ushort4 u;
    u.x = f2bf(f.x); u.y = f2bf(f.y); u.z = f2bf(f.z); u.w = f2bf(f.w);
    *(ushort4*)(w2b + i) = u;
  }
}

// ---------------------------------------------------------------------------
// V transpose: src [4][2048][512] -> dst [4][512][2048] (bf16)
// ---------------------------------------------------------------------------
__global__ __launch_bounds__(256) void transpose_v(const unsigned short* __restrict__ src,
                                                   unsigned short* __restrict__ dst) {
  __shared__ unsigned short t[64][66];
  const int n0 = blockIdx.x * 64, e0 = blockIdx.y * 64;
  const unsigned short* s = src + (size_t)blockIdx.z * 2048 * 512;
  unsigned short* d = dst + (size_t)blockIdx.z * 512 * 2048;
  const int tc = threadIdx.x & 15;
  const int tr = threadIdx.x >> 4;
#pragma unroll
  for (int rr = 0; rr < 64; rr += 16) {
    ushort4 u = *(const ushort4*)(s + (size_t)(n0 + tr + rr) * 512 + e0 + tc * 4);
    t[tr + rr][tc * 4 + 0] = u.x;
    t[tr + rr][tc * 4 + 1] = u.y;
    t[tr + rr][tc * 4 + 2] = u.z;
    t[tr + rr][tc * 4 + 3] = u.w;
  }
  __syncthreads();
#pragma unroll
  for (int rr = 0; rr < 64; rr += 16) {
    ushort4 u;
    u.x = t[tc * 4 + 0][tr + rr];
    u.y = t[tc * 4 + 1][tr + rr];
    u.z = t[tc * 4 + 2][tr + rr];
    u.w = t[tc * 4 + 3][tr + rr];
    *(ushort4*)(d + (size_t)(e0 + tr + rr) * 2048 + n0 + tc * 4) = u;
  }
}

// ---------------------------------------------------------------------------
// Causal row softmax in-place on sim [4][2048][2048] bf16. One wave per row;
// zero-fills to the 128-tile bound so PV can run full tiles with a K limit.
// ---------------------------------------------------------------------------
__global__ __launch_bounds__(256) void softmax_causal(unsigned short* __restrict__ sim) {
  const int lane = threadIdx.x & 63;
  const int rowg = blockIdx.x * 4 + (threadIdx.x >> 6);
  const int i = rowg & 2047;
  unsigned short* row = sim + (size_t)rowg * 2048;
  const int nv = i + 1;
  const int tb = ((i >> 7) + 1) << 7;
  const int nc = (nv + 255) >> 8;
  const int ns = (tb + 255) >> 8;

  float v[32];
  float m = -1e30f;
#pragma unroll
  for (int c = 0; c < 8; ++c) {
    if (c < nc) {
      const int j0 = c * 256 + lane * 4;
      ushort4 u = *(const ushort4*)(row + j0);
      float f0 = bf2f(u.x), f1 = bf2f(u.y), f2 = bf2f(u.z), f3 = bf2f(u.w);
      v[c * 4 + 0] = (j0 + 0 < nv) ? f0 : -1e30f;
      v[c * 4 + 1] = (j0 + 1 < nv) ? f1 : -1e30f;
      v[c * 4 + 2] = (j0 + 2 < nv) ? f2 : -1e30f;
      v[c * 4 + 3] = (j0 + 3 < nv) ? f3 : -1e30f;
      m = fmaxf(m, fmaxf(fmaxf(v[c * 4], v[c * 4 + 1]), fmaxf(v[c * 4 + 2], v[c * 4 + 3])));
    }
  }
#pragma unroll
  for (int s = 32; s >= 1; s >>= 1) m = fmaxf(m, __shfl_xor(m, s));
  float sum = 0.f;
#pragma unroll
  for (int c = 0; c < 8; ++c) {
    if (c < nc) {
#pragma unroll
      for (int e = 0; e < 4; ++e) {
        float p = __expf(v[c * 4 + e] - m);
        v[c * 4 + e] = p;
        sum += p;
      }
    }
  }
#pragma unroll
  for (int s = 32; s >= 1; s >>= 1) sum += __shfl_xor(sum, s);
  const float inv = 1.0f / sum;
#pragma unroll
  for (int c = 0; c < 8; ++c) {
    if (c < ns) {
      const int j0 = c * 256 + lane * 4;
      ushort4 u;
      if (c < nc) {
        u.x = f2bf(v[c * 4 + 0] * inv);
        u.y = f2bf(v[c * 4 + 1] * inv);
        u.z = f2bf(v[c * 4 + 2] * inv);
        u.w = f2bf(v[c * 4 + 3] * inv);
      } else {
        u.x = u.y = u.z = u.w = 0;
      }
      *(ushort4*)(row + j0) = u;
    }
  }
}

// ---------------------------------------------------------------------------
// bf16 B^T GEMM: C[M,N] = A[M,K] * B[N,K]^T. Tile BMxBN (BM,BN mult of 64),
// BK=32, 4 waves (2x2), per-wave (BM/2)x(BN/2). 3 LDS buffers, 2 tiles in
// flight, steady-state wait = vmcnt(loads/tile), swizzled LDS slots.
// EPI: 0 QKV scatter (q*scale|k|v)  1 sim bf16  2 attn-out bf16  3 fp32+bias
// ---------------------------------------------------------------------------
template <int EPI, int BM, int BN>
__global__ __launch_bounds__(256) void gemm_bt(
    const unsigned short* __restrict__ A, const unsigned short* __restrict__ B,
    int M, int N, int K, long strideA, long strideB, int klim, int causal,
    void* __restrict__ O0, void* __restrict__ O1, void* __restrict__ O2,
    const float* __restrict__ bias, float qscale) {
  const int bm = blockIdx.x, bn = blockIdx.y, bz = blockIdx.z;
  if (causal && bn > bm) return;
  const int tid = threadIdx.x, lane = tid & 63, wave = tid >> 6;
  const int wr = wave >> 1, wc = wave & 1;
  constexpr int FM = BM / 32, FN = BN / 32;  // 16x16 frags per wave
  constexpr int AR = BM / 64, BR = BN / 64;  // 4KB staging rounds
  constexpr int L = AR + BR;                 // global_load_lds per tile per thread

  __shared__ alignas(16) unsigned short As[3][BM * 32];
  __shared__ alignas(16) unsigned short Bs[3][BN * 32];

  const unsigned short* Ab = A + (size_t)bz * strideA + (size_t)bm * BM * K;
  const unsigned short* Bb = B + (size_t)bz * strideB + (size_t)bn * BN * K;

  const int kmax = klim ? min(K, (bm + 1) * BM) : K;
  const int nkt = kmax >> 5;

  auto stage = [&](int buf, int kt) {
    const int loff = tid * 16;
#pragma unroll
    for (int i = 0; i < AR; ++i) {
      const int o = i * 4096 + loff;
      const int r = o >> 6;
      const int sl = ((o >> 4) & 3) ^ ((r >> 1) & 3);  // logical slot for phys o
      __builtin_amdgcn_global_load_lds(
          (const __attribute__((address_space(1))) void*)(
              (const char*)(Ab + (size_t)r * K) + (size_t)kt * 64 + sl * 16),
          (__attribute__((address_space(3))) void*)((char*)As[buf] + o), 16, 0, 0);
    }
#pragma unroll
    for (int i = 0; i < BR; ++i) {
      const int o = i * 4096 + loff;
      const int r = o >> 6;
      const int sl = ((o >> 4) & 3) ^ ((r >> 1) & 3);
      __builtin_amdgcn_global_load_lds(
          (const __attribute__((address_space(1))) void*)(
              (const char*)(Bb + (size_t)r * K) + (size_t)kt * 64 + sl * 16),
          (__attribute__((address_space(3))) void*)((char*)Bs[buf] + o), 16, 0, 0);
    }
  };

  f32x4_t acc[FM][FN] = {};

  stage(0, 0);
  if (nkt > 1) stage(1, 1);
  int cur = 0;
  for (int kt = 0; kt < nkt; ++kt) {
    if (kt + 1 < nkt) wait_vmcnt<L>();  // tile kt landed; kt+1 stays in flight
    else wait_vmcnt<0>();
    __builtin_amdgcn_s_barrier();

    bf16x8_t av[FM], bv[FN];
#pragma unroll
    for (int f = 0; f < FM; ++f) {
      const int row = wr * (BM / 2) + f * 16 + (lane & 15);
      const int sp = (lane >> 4) ^ ((row >> 1) & 3);
      av[f] = *(const bf16x8_t*)((const char*)As[cur] + row * 64 + sp * 16);
    }
#pragma unroll
    for (int f = 0; f < FN; ++f) {
      const int row = wc * (BN / 2) + f * 16 + (lane & 15);
      const int sp = (lane >> 4) ^ ((row >> 1) & 3);
      bv[f] = *(const bf16x8_t*)((const char*)Bs[cur] + row * 64 + sp * 16);
    }
    if (kt + 2 < nkt) {
      int nb = cur + 2;
      if (nb >= 3) nb -= 3;
      stage(nb, kt + 2);  // overwrites buf of tile kt-1: safe post-barrier
    }
    asm volatile("s_waitcnt lgkmcnt(0)" ::: "memory");
    __builtin_amdgcn_sched_barrier(0);
    __builtin_amdgcn_s_setprio(1);
#pragma unroll
    for (int fi = 0; fi < FM; ++fi)
#pragma unroll
      for (int fj = 0; fj < FN; ++fj)
        acc[fi][fj] = __builtin_amdgcn_mfma_f32_16x16x32_bf16(av[fi], bv[fj], acc[fi][fj], 0, 0, 0);
    __builtin_amdgcn_s_setprio(0);
    __builtin_amdgcn_sched_barrier(0);
    cur = (cur + 1 == 3) ? 0 : cur + 1;
  }

#pragma unroll
  for (int fi = 0; fi < FM; ++fi) {
    const int row_l = wr * (BM / 2) + fi * 16 + ((lane >> 4) << 2);
#pragma unroll
    for (int fj = 0; fj < FN; ++fj) {
      const int col = bn * BN + wc * (BN / 2) + fj * 16 + (lane & 15);
#pragma unroll
      for (int r = 0; r < 4; ++r) {
        const int row = bm * BM + row_l + r;
        float v = acc[fi][fj][r];
        if constexpr (EPI == 0) {
          if (col < 512)
            ((unsigned short*)O0)[(size_t)row * 512 + col] = f2bf(v * qscale);
          else if (col < 1024)
            ((unsigned short*)O1)[(size_t)row * 512 + (col - 512)] = f2bf(v);
          else
            ((unsigned short*)O2)[(size_t)row * 512 + (col - 1024)] = f2bf(v);
        } else if constexpr (EPI == 1) {
          ((unsigned short*)O0)[(size_t)bz * 2048 * 2048 + (size_t)row * 2048 + col] = f2bf(v);
        } else if constexpr (EPI == 2) {
          ((unsigned short*)O0)[(size_t)bz * 2048 * 512 + (size_t)row * 512 + col] = f2bf(v);
        } else {
          ((float*)O0)[(size_t)row * 1024 + col] = v + bias[col];
        }
      }
    }
  }
}

// ---------------------------------------------------------------------------
extern "C" void kernel_launch(void* const* d_in, const int* in_sizes, int n_in,
                              void* d_out, int out_size, void* d_ws, size_t ws_size,
                              hipStream_t stream) {
  const float* x = (const float*)d_in[0];
  const float* w_qkv = (const float*)d_in[1];
  const float* w_out = (const float*)d_in[2];
  const float* b_out = (const float*)d_in[3];
  float* out = (float*)d_out;

  char* ws = (char*)d_ws;
  size_t off = 0;
  auto alloc = [&](size_t bytes) {
    size_t o = off;
    off += (bytes + 255) & ~(size_t)255;
    return o;
  };
  unsigned short* xb = (unsigned short*)(ws + alloc((size_t)8192 * 1024 * 2));
  unsigned short* wqkvb = (unsigned short*)(ws + alloc((size_t)1536 * 1024 * 2));
  unsigned short* woutb = (unsigned short*)(ws + alloc((size_t)1024 * 512 * 2));
  unsigned short* qb = (unsigned short*)(ws + alloc((size_t)8192 * 512 * 2));
  unsigned short* kb = (unsigned short*)(ws + alloc((size_t)8192 * 512 * 2));
  unsigned short* vb = (unsigned short*)(ws + alloc((size_t)8192 * 512 * 2));
  unsigned short* vtb = (unsigned short*)(ws + alloc((size_t)8192 * 512 * 2));
  unsigned short* sim = (unsigned short*)(ws + alloc((size_t)4 * 2048 * 2048 * 2));
  unsigned short* ao = (unsigned short*)(ws + alloc((size_t)8192 * 512 * 2));

  const float scale = 1.0f / sqrtf(512.0f);

  cvt_all<<<2048, 256, 0, stream>>>(x, xb, 8192 * 1024, w_qkv, wqkvb, 1536 * 1024,
                                    w_out, woutb, 1024 * 512);

  // QKV: [8192,1536] = xb[8192,1024] * wqkvb^T — 128x192 tile, 512 blocks (2/CU)
  gemm_bt<0, 128, 192><<<dim3(64, 8, 1), 256, 0, stream>>>(
      xb, wqkvb, 8192, 1536, 1024, 0, 0, 0, 0, qb, kb, vb, nullptr, scale);

  transpose_v<<<dim3(32, 8, 4), 256, 0, stream>>>(vb, vtb);

  // sim = q*scale @ k^T, causal tile skip
  gemm_bt<1, 128, 128><<<dim3(16, 16, 4), 256, 0, stream>>>(
      qb, kb, 2048, 2048, 512, (long)2048 * 512, (long)2048 * 512,
      0, 1, sim, nullptr, nullptr, nullptr, 0.f);

  softmax_causal<<<2048, 256, 0, stream>>>(sim);

  // attn @ v : 128x64 tile, K causal-limited
  gemm_bt<2, 128, 64><<<dim3(16, 8, 4), 256, 0, stream>>>(
      sim, vtb, 2048, 512, 2048, (long)2048 * 2048, (long)512 * 2048,
      1, 0, ao, nullptr, nullptr, nullptr, 0.f);

  // out = ao @ w_out^T + b
  gemm_bt<3, 128, 128><<<dim3(64, 8, 1), 256, 0, stream>>>(
      ao, woutb, 8192, 1024, 512, 0, 0, 0, 0, out, nullptr, nullptr, b_out, 0.f);
}